// Round 6
// baseline (193.353 us; speedup 1.0000x reference)
//
#include <hip/hip_runtime.h>

typedef _Float16 half_t;
typedef _Float16 h2 __attribute__((ext_vector_type(2)));

constexpr int Nc = 4, Cc = 256, Hc = 96, Wc = 160;
constexpr int RXc = 4, RYc = 4;
constexpr int WIN = 10;          // (2*RX+1)+1 integer grid per axis
constexpr int NPOS = WIN * WIN;  // 100
constexpr int Dc = 81;           // 9*9 displacements
constexpr int PIX = Hc * Wc;     // 15360
constexpr int NPIX = Nc * PIX;   // 61440

// Tiled transpose fp32->fp32: A[R][S] -> B[S][R] per batch (blockIdx.z)
__global__ __launch_bounds__(256) void transpose_rs(const float* __restrict__ in,
                                                    float* __restrict__ out,
                                                    int R, int S) {
    __shared__ float tile[32][33];
    size_t base = (size_t)blockIdx.z * (size_t)R * (size_t)S;
    const float* A = in + base;
    float* B = out + base;
    int s0 = blockIdx.x * 32;
    int r0 = blockIdx.y * 32;
    int tx = threadIdx.x, ty = threadIdx.y;
    #pragma unroll
    for (int i = ty; i < 32; i += 8) {
        int r = r0 + i, s = s0 + tx;
        if (r < R && s < S) tile[i][tx] = A[(size_t)r * S + s];
    }
    __syncthreads();
    #pragma unroll
    for (int i = ty; i < 32; i += 8) {
        int s = s0 + i, r = r0 + tx;
        if (s < S && r < R) B[(size_t)s * R + r] = tile[tx][i];
    }
}

// Tiled transpose + cast for BOTH features in one launch:
// z in [0, 2*Nc): batch = z>>1, src/dst pair = z&1.
// A[C][P] fp32 -> B[P][C] fp16, R=Cc (mult of 32), S=PIX (mult of 32).
__global__ __launch_bounds__(256) void transpose_cvt2(const float* __restrict__ in1,
                                                      const float* __restrict__ in2,
                                                      half_t* __restrict__ out1,
                                                      half_t* __restrict__ out2,
                                                      int R, int S) {
    __shared__ float tile[32][33];
    int b = blockIdx.z >> 1;
    int which = blockIdx.z & 1;
    const float* A = (which ? in2 : in1) + (size_t)b * R * S;
    half_t* B = (which ? out2 : out1) + (size_t)b * R * S;
    int s0 = blockIdx.x * 32;
    int r0 = blockIdx.y * 32;
    int tx = threadIdx.x, ty = threadIdx.y;
    #pragma unroll
    for (int i = ty; i < 32; i += 8) {
        int r = r0 + i, s = s0 + tx;
        tile[i][tx] = A[(size_t)r * S + s];
    }
    __syncthreads();
    #pragma unroll
    for (int i = ty; i < 32; i += 8) {
        int s = s0 + i;
        int rr = r0 + 2 * tx;
        if (tx < 16) {
            h2 v;
            v.x = (half_t)tile[2 * tx][i];
            v.y = (half_t)tile[2 * tx + 1][i];
            *(h2*)(B + (size_t)s * R + rr) = v;
        }
    }
}

// Main: one block per pixel. f1t/f2t are NHWC fp16. cv is [N,H,W,D] fp32.
// 8-lane groups, full 128B line per gather instr; offsets precomputed in LDS;
// 4 passes fully unrolled with 2 register buffers -> 8 loads in flight.
__global__ __launch_bounds__(256) void cv_main(const half_t* __restrict__ f1t,
                                               const half_t* __restrict__ f2t,
                                               const float* __restrict__ ofs,
                                               float* __restrict__ cv) {
    // XCD-aware swizzle: contiguous pixel chunk per XCD (NPIX % 8 == 0)
    int nwg = gridDim.x;
    int bid = blockIdx.x;
    int cpx = nwg >> 3;
    int pix = (bid & 7) * cpx + (bid >> 3);

    int n = pix / PIX;
    int hw = pix - n * PIX;
    int h = hw / Wc, w = hw - h * Wc;
    int tid = threadIdx.x;
    int lane = tid & 7;   // 8 lanes per position -> 128B contiguous per instr
    int group = tid >> 3; // 0..31

    __shared__ half_t f1s[Cc];  // 512 B
    __shared__ float gs[NPOS];
    __shared__ int poff[128];   // byte offset in f2t batch plane, -1 if OOB/pad

    // Stage f1 vector (512B) cooperatively, coalesced.
    if (tid < Cc / 8)
        ((float4*)f1s)[tid] = ((const float4*)(f1t + (size_t)pix * Cc))[tid];

    float ofx = ofs[(size_t)(n * 2 + 0) * PIX + hw];
    float ofy = ofs[(size_t)(n * 2 + 1) * PIX + hw];
    float xc = (float)w + ofx;
    float yc = (float)h + ofy;
    float x0f = floorf(xc), y0f = floorf(yc);
    float wx = xc - x0f, wy = yc - y0f;
    int xi0 = (int)x0f - RXc;
    int yi0 = (int)y0f - RYc;

    // Precompute the 100 gather offsets once (block-uniform values); pad to 128.
    if (tid < 128) {
        int v = -1;
        if (tid < NPOS) {
            int j = tid / WIN;
            int i = tid - j * WIN;
            int x = xi0 + i, y = yi0 + j;
            if (x >= 0 && x < Wc && y >= 0 && y < Hc)
                v = (y * Wc + x) * (int)(Cc * sizeof(half_t));
        }
        poff[tid] = v;
    }
    __syncthreads();

    // This lane's f1 fragment: loop-invariant -> read from LDS ONCE.
    const float4* f1v = (const float4*)f1s;
    float4 f1r[4];
    #pragma unroll
    for (int c = 0; c < 4; ++c) f1r[c] = f1v[c * 8 + lane];

    const char* f2n = (const char*)(f2t + (size_t)n * (Hc * Wc) * Cc);

    int off0 = poff[group];
    int off1 = poff[32 + group];
    int off2 = poff[64 + group];
    int off3 = poff[96 + group];

    auto ld = [&](float4* buf, int off) {
        const float4* p = (const float4*)(f2n + (off < 0 ? 0 : off));
        buf[0] = p[lane];
        buf[1] = p[8 + lane];
        buf[2] = p[16 + lane];
        buf[3] = p[24 + lane];
    };
    auto dot = [&](const float4* buf, int off) -> float {
        float acc0 = 0.f, acc1 = 0.f;
        #pragma unroll
        for (int c = 0; c < 4; ++c) {
            h2* ah = (h2*)&f1r[c];
            h2* bh = (h2*)&buf[c];
            acc0 = __builtin_amdgcn_fdot2(ah[0], bh[0], acc0, false);
            acc1 = __builtin_amdgcn_fdot2(ah[1], bh[1], acc1, false);
            acc0 = __builtin_amdgcn_fdot2(ah[2], bh[2], acc0, false);
            acc1 = __builtin_amdgcn_fdot2(ah[3], bh[3], acc1, false);
        }
        return (off >= 0) ? (acc0 + acc1) : 0.f;
    };
    auto red = [&](float g, int pos) {
        g += __shfl_xor(g, 1);
        g += __shfl_xor(g, 2);
        g += __shfl_xor(g, 4);
        if (lane == 0 && pos < NPOS) gs[pos] = g;
    };

    float4 bA[4], bB[4];
    ld(bA, off0);            // pass 0 loads
    ld(bB, off1);            // pass 1 loads (8 lines in flight)
    float g0 = dot(bA, off0);
    ld(bA, off2);            // pass 2 loads overlap pass-1 compute
    float g1 = dot(bB, off1);
    ld(bB, off3);            // pass 3 loads overlap pass-2 compute
    float g2 = dot(bA, off2);
    float g3 = dot(bB, off3);

    red(g0, group);
    red(g1, 32 + group);
    red(g2, 64 + group);
    red(g3, 96 + group);
    __syncthreads();

    if (tid < Dc) {
        int dyi = tid / 9, dxi = tid - dyi * 9;
        float g00 = gs[dyi * WIN + dxi];
        float g01 = gs[dyi * WIN + dxi + 1];
        float g10 = gs[(dyi + 1) * WIN + dxi];
        float g11 = gs[(dyi + 1) * WIN + dxi + 1];
        float v = (g00 * (1.f - wx) + g01 * wx) * (1.f - wy) +
                  (g10 * (1.f - wx) + g11 * wx) * wy;
        cv[(size_t)pix * Dc + tid] = v;
    }
}

// Fallback (workspace too small): direct NCHW fp32, uncoalesced but correct.
__global__ __launch_bounds__(128) void cv_naive(const float* __restrict__ f1,
                                                const float* __restrict__ f2,
                                                const float* __restrict__ ofs,
                                                float* __restrict__ out) {
    int pix = blockIdx.x;
    int n = pix / PIX;
    int hw = pix - n * PIX;
    int h = hw / Wc, w = hw - h * Wc;
    int tid = threadIdx.x;

    __shared__ float gs[NPOS];

    float ofx = ofs[(size_t)(n * 2 + 0) * PIX + hw];
    float ofy = ofs[(size_t)(n * 2 + 1) * PIX + hw];
    float xc = (float)w + ofx;
    float yc = (float)h + ofy;
    float x0f = floorf(xc), y0f = floorf(yc);
    float wx = xc - x0f, wy = yc - y0f;
    int xi0 = (int)x0f - RXc;
    int yi0 = (int)y0f - RYc;

    if (tid < NPOS) {
        int j = tid / WIN, i = tid - (tid / WIN) * WIN;
        int x = xi0 + i, y = yi0 + j;
        float g = 0.f;
        if (x >= 0 && x < Wc && y >= 0 && y < Hc) {
            const float* p1 = f1 + (size_t)n * Cc * PIX + hw;
            const float* p2 = f2 + (size_t)n * Cc * PIX + (size_t)y * Wc + x;
            for (int c = 0; c < Cc; ++c)
                g += p1[(size_t)c * PIX] * p2[(size_t)c * PIX];
        }
        gs[tid] = g;
    }
    __syncthreads();

    if (tid < Dc) {
        int dyi = tid / 9, dxi = tid - dyi * 9;
        float g00 = gs[dyi * WIN + dxi];
        float g01 = gs[dyi * WIN + dxi + 1];
        float g10 = gs[(dyi + 1) * WIN + dxi];
        float g11 = gs[(dyi + 1) * WIN + dxi + 1];
        float v = (g00 * (1.f - wx) + g01 * wx) * (1.f - wy) +
                  (g10 * (1.f - wx) + g11 * wx) * wy;
        out[(size_t)(n * Dc + tid) * PIX + hw] = v;
    }
}

extern "C" void kernel_launch(void* const* d_in, const int* in_sizes, int n_in,
                              void* d_out, int out_size, void* d_ws, size_t ws_size,
                              hipStream_t stream) {
    const float* f1 = (const float*)d_in[0];
    const float* f2 = (const float*)d_in[1];
    const float* ofs = (const float*)d_in[2];
    float* out = (float*)d_out;

    size_t feat_elems = (size_t)Nc * Cc * PIX;  // 15,728,640
    size_t cv_elems = (size_t)NPIX * Dc;        // 4,976,640
    // fp16 f1t + fp16 f2t + fp32 cvt
    size_t need = 2 * feat_elems * sizeof(half_t) + cv_elems * sizeof(float);

    if (ws_size >= need) {
        half_t* f1t = (half_t*)d_ws;
        half_t* f2t = f1t + feat_elems;
        float* cvt = (float*)(f2t + feat_elems);
        dim3 tb(32, 8);
        // NCHW -> NHWC fp16 for both f1 and f2 in one launch
        transpose_cvt2<<<dim3(PIX / 32, Cc / 32, 2 * Nc), tb, 0, stream>>>(
            f1, f2, f1t, f2t, Cc, PIX);
        cv_main<<<NPIX, 256, 0, stream>>>(f1t, f2t, ofs, cvt);
        // [P][D] -> [D][P] fp32
        transpose_rs<<<dim3((Dc + 31) / 32, PIX / 32, Nc), tb, 0, stream>>>(cvt, out, PIX, Dc);
    } else {
        cv_naive<<<NPIX, 128, 0, stream>>>(f1, f2, ofs, out);
    }
}

// Round 7
// 152.706 us; speedup vs baseline: 1.2662x; 1.2662x over previous
//
#include <hip/hip_runtime.h>

typedef _Float16 half_t;
typedef _Float16 h2 __attribute__((ext_vector_type(2)));

constexpr int Nc = 4, Cc = 256, Hc = 96, Wc = 160;
constexpr int RXc = 4, RYc = 4;
constexpr int WIN = 10;          // (2*RX+1)+1 integer grid per axis
constexpr int NPOS = WIN * WIN;  // 100
constexpr int Dc = 81;           // 9*9 displacements
constexpr int PIX = Hc * Wc;     // 15360
constexpr int NPIX = Nc * PIX;   // 61440

// Tiled transpose fp32->fp32: A[R][S] -> B[S][R] per batch (blockIdx.z)
__global__ __launch_bounds__(256) void transpose_rs(const float* __restrict__ in,
                                                    float* __restrict__ out,
                                                    int R, int S) {
    __shared__ float tile[32][33];
    size_t base = (size_t)blockIdx.z * (size_t)R * (size_t)S;
    const float* A = in + base;
    float* B = out + base;
    int s0 = blockIdx.x * 32;
    int r0 = blockIdx.y * 32;
    int tx = threadIdx.x, ty = threadIdx.y;
    #pragma unroll
    for (int i = ty; i < 32; i += 8) {
        int r = r0 + i, s = s0 + tx;
        if (r < R && s < S) tile[i][tx] = A[(size_t)r * S + s];
    }
    __syncthreads();
    #pragma unroll
    for (int i = ty; i < 32; i += 8) {
        int s = s0 + i, r = r0 + tx;
        if (s < S && r < R) B[(size_t)s * R + r] = tile[tx][i];
    }
}

// Tiled transpose + cast for BOTH features in one launch:
// z in [0, 2*Nc): batch = z>>1, src/dst pair = z&1.
// A[C][P] fp32 -> B[P][C] fp16, R=Cc (mult of 32), S=PIX (mult of 32).
__global__ __launch_bounds__(256) void transpose_cvt2(const float* __restrict__ in1,
                                                      const float* __restrict__ in2,
                                                      half_t* __restrict__ out1,
                                                      half_t* __restrict__ out2,
                                                      int R, int S) {
    __shared__ float tile[32][33];
    int b = blockIdx.z >> 1;
    int which = blockIdx.z & 1;
    const float* A = (which ? in2 : in1) + (size_t)b * R * S;
    half_t* B = (which ? out2 : out1) + (size_t)b * R * S;
    int s0 = blockIdx.x * 32;
    int r0 = blockIdx.y * 32;
    int tx = threadIdx.x, ty = threadIdx.y;
    #pragma unroll
    for (int i = ty; i < 32; i += 8) {
        int r = r0 + i, s = s0 + tx;
        tile[i][tx] = A[(size_t)r * S + s];
    }
    __syncthreads();
    #pragma unroll
    for (int i = ty; i < 32; i += 8) {
        int s = s0 + i;
        int rr = r0 + 2 * tx;
        if (tx < 16) {
            h2 v;
            v.x = (half_t)tile[2 * tx][i];
            v.y = (half_t)tile[2 * tx + 1][i];
            *(h2*)(B + (size_t)s * R + rr) = v;
        }
    }
}

// Main: one block per pixel. f1t/f2t are NHWC fp16. cv is [N,H,W,D] fp32.
// 8-lane groups, full 128B line per gather instr; position byte-offsets
// precomputed once into LDS (block-uniform across passes).
__global__ __launch_bounds__(256) void cv_main(const half_t* __restrict__ f1t,
                                               const half_t* __restrict__ f2t,
                                               const float* __restrict__ ofs,
                                               float* __restrict__ cv) {
    // XCD-aware swizzle: contiguous pixel chunk per XCD (NPIX % 8 == 0)
    int nwg = gridDim.x;
    int bid = blockIdx.x;
    int cpx = nwg >> 3;
    int pix = (bid & 7) * cpx + (bid >> 3);

    int n = pix / PIX;
    int hw = pix - n * PIX;
    int h = hw / Wc, w = hw - h * Wc;
    int tid = threadIdx.x;
    int lane = tid & 7;   // 8 lanes per position -> 128B contiguous per instr
    int group = tid >> 3; // 0..31

    __shared__ half_t f1s[Cc];  // 512 B
    __shared__ float gs[NPOS];
    __shared__ int poff[NPOS];  // byte offset in f2t batch plane, or -1 if OOB

    // Stage f1 vector (512B) cooperatively, coalesced.
    if (tid < Cc / 8)
        ((float4*)f1s)[tid] = ((const float4*)(f1t + (size_t)pix * Cc))[tid];

    float ofx = ofs[(size_t)(n * 2 + 0) * PIX + hw];
    float ofy = ofs[(size_t)(n * 2 + 1) * PIX + hw];
    float xc = (float)w + ofx;
    float yc = (float)h + ofy;
    float x0f = floorf(xc), y0f = floorf(yc);
    float wx = xc - x0f, wy = yc - y0f;
    int xi0 = (int)x0f - RXc;
    int yi0 = (int)y0f - RYc;

    // Precompute the 100 gather offsets once (block-uniform values).
    if (tid < NPOS) {
        int j = tid / WIN;
        int i = tid - j * WIN;
        int x = xi0 + i, y = yi0 + j;
        bool valid = (x >= 0) & (x < Wc) & (y >= 0) & (y < Hc);
        poff[tid] = valid ? (int)(((unsigned)(y * Wc + x)) * (Cc * sizeof(half_t))) : -1;
    }
    __syncthreads();

    // This lane's f1 fragment: loop-invariant -> read from LDS ONCE.
    const float4* f1v = (const float4*)f1s;
    float4 f1r[4];
    #pragma unroll
    for (int c = 0; c < 4; ++c) f1r[c] = f1v[c * 8 + lane];

    const char* f2n = (const char*)(f2t + (size_t)n * (Hc * Wc) * Cc);

    #pragma unroll
    for (int pass = 0; pass < 4; ++pass) {
        int pos = pass * 32 + group;
        int off = (pos < NPOS) ? poff[pos] : -1;  // broadcast ds_read
        float g = 0.f;
        if (off >= 0) {
            const float4* f2v = (const float4*)(f2n + off);
            float acc0 = 0.f, acc1 = 0.f;
            #pragma unroll
            for (int c = 0; c < 4; ++c) {
                float4 b = f2v[c * 8 + lane];  // 16B of the position's 128B chunk
                h2* ah = (h2*)&f1r[c];
                h2* bh = (h2*)&b;
                acc0 = __builtin_amdgcn_fdot2(ah[0], bh[0], acc0, false);
                acc1 = __builtin_amdgcn_fdot2(ah[1], bh[1], acc1, false);
                acc0 = __builtin_amdgcn_fdot2(ah[2], bh[2], acc0, false);
                acc1 = __builtin_amdgcn_fdot2(ah[3], bh[3], acc1, false);
            }
            g = acc0 + acc1;
        }
        if (pos < NPOS) {
            g += __shfl_xor(g, 1);
            g += __shfl_xor(g, 2);
            g += __shfl_xor(g, 4);
            if (lane == 0) gs[pos] = g;
        }
    }
    __syncthreads();

    if (tid < Dc) {
        int dyi = tid / 9, dxi = tid - dyi * 9;
        float g00 = gs[dyi * WIN + dxi];
        float g01 = gs[dyi * WIN + dxi + 1];
        float g10 = gs[(dyi + 1) * WIN + dxi];
        float g11 = gs[(dyi + 1) * WIN + dxi + 1];
        float v = (g00 * (1.f - wx) + g01 * wx) * (1.f - wy) +
                  (g10 * (1.f - wx) + g11 * wx) * wy;
        cv[(size_t)pix * Dc + tid] = v;
    }
}

// Fallback (workspace too small): direct NCHW fp32, uncoalesced but correct.
__global__ __launch_bounds__(128) void cv_naive(const float* __restrict__ f1,
                                                const float* __restrict__ f2,
                                                const float* __restrict__ ofs,
                                                float* __restrict__ out) {
    int pix = blockIdx.x;
    int n = pix / PIX;
    int hw = pix - n * PIX;
    int h = hw / Wc, w = hw - h * Wc;
    int tid = threadIdx.x;

    __shared__ float gs[NPOS];

    float ofx = ofs[(size_t)(n * 2 + 0) * PIX + hw];
    float ofy = ofs[(size_t)(n * 2 + 1) * PIX + hw];
    float xc = (float)w + ofx;
    float yc = (float)h + ofy;
    float x0f = floorf(xc), y0f = floorf(yc);
    float wx = xc - x0f, wy = yc - y0f;
    int xi0 = (int)x0f - RXc;
    int yi0 = (int)y0f - RYc;

    if (tid < NPOS) {
        int j = tid / WIN, i = tid - (tid / WIN) * WIN;
        int x = xi0 + i, y = yi0 + j;
        float g = 0.f;
        if (x >= 0 && x < Wc && y >= 0 && y < Hc) {
            const float* p1 = f1 + (size_t)n * Cc * PIX + hw;
            const float* p2 = f2 + (size_t)n * Cc * PIX + (size_t)y * Wc + x;
            for (int c = 0; c < Cc; ++c)
                g += p1[(size_t)c * PIX] * p2[(size_t)c * PIX];
        }
        gs[tid] = g;
    }
    __syncthreads();

    if (tid < Dc) {
        int dyi = tid / 9, dxi = tid - dyi * 9;
        float g00 = gs[dyi * WIN + dxi];
        float g01 = gs[dyi * WIN + dxi + 1];
        float g10 = gs[(dyi + 1) * WIN + dxi];
        float g11 = gs[(dyi + 1) * WIN + dxi + 1];
        float v = (g00 * (1.f - wx) + g01 * wx) * (1.f - wy) +
                  (g10 * (1.f - wx) + g11 * wx) * wy;
        out[(size_t)(n * Dc + tid) * PIX + hw] = v;
    }
}

extern "C" void kernel_launch(void* const* d_in, const int* in_sizes, int n_in,
                              void* d_out, int out_size, void* d_ws, size_t ws_size,
                              hipStream_t stream) {
    const float* f1 = (const float*)d_in[0];
    const float* f2 = (const float*)d_in[1];
    const float* ofs = (const float*)d_in[2];
    float* out = (float*)d_out;

    size_t feat_elems = (size_t)Nc * Cc * PIX;  // 15,728,640
    size_t cv_elems = (size_t)NPIX * Dc;        // 4,976,640
    // fp16 f1t + fp16 f2t + fp32 cvt
    size_t need = 2 * feat_elems * sizeof(half_t) + cv_elems * sizeof(float);

    if (ws_size >= need) {
        half_t* f1t = (half_t*)d_ws;
        half_t* f2t = f1t + feat_elems;
        float* cvt = (float*)(f2t + feat_elems);
        dim3 tb(32, 8);
        // NCHW -> NHWC fp16 for both f1 and f2 in one launch
        transpose_cvt2<<<dim3(PIX / 32, Cc / 32, 2 * Nc), tb, 0, stream>>>(
            f1, f2, f1t, f2t, Cc, PIX);
        cv_main<<<NPIX, 256, 0, stream>>>(f1t, f2t, ofs, cvt);
        // [P][D] -> [D][P] fp32
        transpose_rs<<<dim3((Dc + 31) / 32, PIX / 32, Nc), tb, 0, stream>>>(cvt, out, PIX, Dc);
    } else {
        cv_naive<<<NPIX, 128, 0, stream>>>(f1, f2, ofs, out);
    }
}